// Round 12
// baseline (5362.596 us; speedup 1.0000x reference)
//
#include <hip/hip_runtime.h>
#include <cstdint>
#include <cstddef>

typedef unsigned short u16;
typedef unsigned int u32;
typedef __attribute__((ext_vector_type(8))) short short8;
typedef __attribute__((ext_vector_type(4))) float f32x4;

#define AGENT_SCOPE __HIP_MEMORY_SCOPE_AGENT
#define SPIN_CAP 20000000
#define POLL_CAP 100000
#define SENT 0xFFFFFFFFu

__device__ __forceinline__ u16 f2bf(float f) {
  u32 u = __float_as_uint(f);
  return (u16)((u + 0x7FFFu + ((u >> 16) & 1u)) >> 16);
}
__device__ __forceinline__ float bf2f(u16 s) { return __uint_as_float(((u32)s) << 16); }
__device__ __forceinline__ float sigm(float x) { return 1.f / (1.f + __expf(-x)); }
__device__ __forceinline__ float tanha(float x) { return 1.f - 2.f / (__expf(2.f * x) + 1.f); }
__device__ __forceinline__ void wait_vm0() { asm volatile("s_waitcnt vmcnt(0)" ::: "memory"); }
__device__ __forceinline__ u32 um(u32 a, u32 b) { return a > b ? a : b; }

// cache-bypassing agent-visible 16B load (R3/R4-verified semantics)
__device__ __forceinline__ uint4 ldx4(const void* p) {
  uint4 r;
  asm volatile("global_load_dwordx4 %0, %1, off sc0 sc1" : "=v"(r) : "v"(p) : "memory");
  return r;
}

// R12 = R6 (zero-shuffle act, verified-correct) with ONE change: ring block
// layout is now HALF-MAJOR — [rowg][hf half][16 batch x 2 pair] — so each
// wave's 32 h-dwords are a contiguous 128B (full-line ownership). R6's +262MB
// WRITE_SIZE regression was partial-line merges from interleaving two waves'
// stores within each 64B line; that sat on the store->visibility path.
// Zero-shuffle act (R5/R6): mfma(W_frag,h_frag), weight row map
// row=(m&3)*512+rowg*8+hf*4+(m>>2) => lane (q,m) holds all 4 gates
// (acc[0..3]=i,f,g,o) of unit hf*4+q, batch m. Act is lane-local (c in reg,
// bias folded into acc init); each wave stores its own h immediately after its
// own MFMAs (h0 releases ~250cy earlier); ONE barrier/step; sH parity-dbuf.
// Decoder recon = 16 MFMAs on wave1 (opW rows on lanes m<2), direct store.
// Poll protocol = R4's (x4 fused detect+transfer, sticky done, sleep backoff).
// Clears/ordering invariants identical to R6 (passed correctness at 5787).
__global__ void __launch_bounds__(256, 1)
lstm_ae_kernel(const float* __restrict__ x,
    const float* __restrict__ eWih0, const float* __restrict__ eWhh0,
    const float* __restrict__ ebi0,  const float* __restrict__ ebh0,
    const float* __restrict__ eWih1, const float* __restrict__ eWhh1,
    const float* __restrict__ ebi1,  const float* __restrict__ ebh1,
    const float* __restrict__ dWhh0,
    const float* __restrict__ dbi0,  const float* __restrict__ dbh0,
    const float* __restrict__ dWih1, const float* __restrict__ dWhh1,
    const float* __restrict__ dbi1,  const float* __restrict__ dbh1,
    const float* __restrict__ tlW,   const float* __restrict__ tlb,
    const float* __restrict__ lhW,   const float* __restrict__ lhb,
    const float* __restrict__ opW,   const float* __restrict__ opb,
    float* __restrict__ out, char* __restrict__ wsb)
{
  __shared__ __align__(16) u16 sH[2][2][16 * 520];  // [parity][layer][b][k]
  __shared__ __align__(16) u16 sX[16 * 136];
  __shared__ float sZ[16 * 64];

  u32* gcnt  = (u32*)wsb;
  float* zbuf= (float*)(wsb + 4096);             // [64][64]
  u32* h0r   = (u32*)(wsb + 32768);              // [3 q][4 col][64 rowg][2 hf][32 dw]
  u32* h1r   = (u32*)(wsb + 229376);             // same (196608 B each)

  const int tid  = threadIdx.x;
  const int col  = blockIdx.x & 3;
  const int rowg = blockIdx.x >> 2;              // 0..63
  const int wid  = tid >> 6;
  const int lane = tid & 63;
  const int m    = lane & 15;
  const int q    = lane >> 4;
  const int qo   = q * 8;
  const int li   = wid >> 1;                     // 0: L0, 1: L1
  const int hf   = wid & 1;                      // unit half (units hf*4..+3)

  // A-fragment weight row for lane index m: gate = m&3, unit j = m>>2
  const int wrA = (m & 3) * 512 + rowg * 8 + hf * 4 + (m >> 2);

  // ---------- helpers ----------
  auto cvt8 = [&](const float* p) -> short8 {
    float4 f0 = *(const float4*)p, f1 = *(const float4*)(p + 4);
    short8 r;
    r[0] = (short)f2bf(f0.x); r[1] = (short)f2bf(f0.y);
    r[2] = (short)f2bf(f0.z); r[3] = (short)f2bf(f0.w);
    r[4] = (short)f2bf(f1.x); r[5] = (short)f2bf(f1.y);
    r[6] = (short)f2bf(f1.z); r[7] = (short)f2bf(f1.w);
    return r;
  };

  // R4 poll: x4 fused detect+transfer, sticky per-ring done, sleep backoff.
  // New scatter for half-major layout: image dword g -> rowg=g>>6, o=g&63,
  // hf=(o>>5)&1, b=(o>>1)&15, pair=o&1 -> LDS dword b*260 + rowg*4 + hf*2+pair.
  auto stage_slot = [&](int q0, int q1, bool p0on, bool p1on, int p) {
    const char* base0 = (const char*)(h0r + ((q0 * 4 + col) << 12)) + tid * 16;
    const char* base1 = (const char*)(h1r + ((q1 * 4 + col) << 12)) + tid * 16;
    uint4 v0[4], v1[4];
    bool d0 = !p0on, d1 = !p1on;
    int it = 0;
    for (;;) {
      if (!d0) {
        #pragma unroll
        for (int i = 0; i < 4; ++i) v0[i] = ldx4(base0 + i * 4096);
      }
      if (!d1) {
        #pragma unroll
        for (int i = 0; i < 4; ++i) v1[i] = ldx4(base1 + i * 4096);
      }
      asm volatile("s_waitcnt vmcnt(0)" ::: "memory");
      __builtin_amdgcn_sched_barrier(0);
      if (!d0) {
        u32 mx = 0;
        #pragma unroll
        for (int i = 0; i < 4; ++i)
          mx = um(mx, um(um(v0[i].x, v0[i].y), um(v0[i].z, v0[i].w)));
        d0 = (mx != SENT);
      }
      if (!d1) {
        u32 mx = 0;
        #pragma unroll
        for (int i = 0; i < 4; ++i)
          mx = um(mx, um(um(v1[i].x, v1[i].y), um(v1[i].z, v1[i].w)));
        d1 = (mx != SENT);
      }
      if ((d0 && d1) || ++it >= POLL_CAP) break;
      __builtin_amdgcn_s_sleep(4);
    }
    u32* dH0 = (u32*)sH[p][0]; u32* dH1 = (u32*)sH[p][1];
    const int rg0 = tid >> 4;                  // rowg of chunk 0
    const int o0  = (tid * 4) & 63;            // block-local dword (mult of 4)
    const int shf = (o0 >> 5) & 1;
    const int smb = (o0 >> 1) & 15;            // batches smb, smb+1
    if (p0on) {
      #pragma unroll
      for (int i = 0; i < 4; ++i) {
        int rb = (rg0 + i * 16) * 4 + shf * 2;
        uint2 w0; w0.x = v0[i].x; w0.y = v0[i].y;
        uint2 w1; w1.x = v0[i].z; w1.y = v0[i].w;
        *(uint2*)(dH0 + smb * 260 + rb)       = w0;
        *(uint2*)(dH0 + (smb + 1) * 260 + rb) = w1;
      }
    }
    if (p1on) {
      #pragma unroll
      for (int i = 0; i < 4; ++i) {
        int rb = (rg0 + i * 16) * 4 + shf * 2;
        uint2 w0; w0.x = v1[i].x; w0.y = v1[i].y;
        uint2 w1; w1.x = v1[i].z; w1.y = v1[i].w;
        *(uint2*)(dH1 + smb * 260 + rb)       = w0;
        *(uint2*)(dH1 + (smb + 1) * 260 + rb) = w1;
      }
    }
  };

  auto clears = [&](int s) {
    if (tid < 64) {
      int cq0 = (s + 1) % 3, cq1 = s % 3;
      __hip_atomic_store(h0r + ((cq0 * 4 + col) << 12) + (rowg << 6) + tid,
                         SENT, __ATOMIC_RELAXED, AGENT_SCOPE);
      __hip_atomic_store(h1r + ((cq1 * 4 + col) << 12) + (rowg << 6) + tid,
                         SENT, __ATOMIC_RELAXED, AGENT_SCOPE);
    }
  };

  auto stage_xt = [&](int s) {
    int b = tid >> 4, seg = tid & 15;
    const float* p = x + (size_t)(col * 16 + b) * 131072 + (size_t)s * 128 + seg * 8;
    float4 f0 = *(const float4*)p, f1 = *(const float4*)(p + 4);
    uint4 v;
    v.x = (u32)f2bf(f0.x) | ((u32)f2bf(f0.y) << 16);
    v.y = (u32)f2bf(f0.z) | ((u32)f2bf(f0.w) << 16);
    v.z = (u32)f2bf(f1.x) | ((u32)f2bf(f1.y) << 16);
    v.w = (u32)f2bf(f1.z) | ((u32)f2bf(f1.w) << 16);
    *(uint4*)(sX + b * 136 + seg * 8) = v;
  };

  auto gbar = [&](u32 target) {
    __syncthreads();
    if (tid == 0) {
      __hip_atomic_fetch_add(gcnt, 1u, __ATOMIC_RELEASE, AGENT_SCOPE);
      int it = 0;
      while (__hip_atomic_load(gcnt, __ATOMIC_RELAXED, AGENT_SCOPE) < target && ++it < SPIN_CAP) {
        __builtin_amdgcn_s_sleep(8);
      }
      (void)__hip_atomic_load(gcnt, __ATOMIC_ACQUIRE, AGENT_SCOPE);
    }
    __syncthreads();
  };

  float cst = 0.f;
  f32x4 bias = {0.f, 0.f, 0.f, 0.f};

  // lane-local act + immediate ring store. Unit hf*4+q, batch m; pair via ^16.
  // HALF-MAJOR store: block offset = hf*32 + m*2 + (q>>1) — each wave's 32
  // dwords are contiguous 128B (full-line ownership, no cross-wave merges).
  auto act_store = [&](f32x4 a0, f32x4 a1, int qs) {
    float gi = a0[0] + a1[0], gf = a0[1] + a1[1];
    float gg = a0[2] + a1[2], go = a0[3] + a1[3];
    cst = sigm(gf) * cst + sigm(gi) * tanha(gg);
    float h = sigm(go) * tanha(cst);
    u16 hbv = f2bf(h);
    u32 ph = __shfl_xor((u32)hbv, 16);           // partner unit q^1
    wait_vm0();                                  // clears drained before data
    if (!(q & 1)) {
      u32* ring = li ? h1r : h0r;
      __hip_atomic_store(ring + ((qs * 4 + col) << 12) + (rowg << 6)
                             + hf * 32 + m * 2 + (q >> 1),
                         (u32)hbv | (ph << 16), __ATOMIC_RELAXED, AGENT_SCOPE);
    }
  };

  short8 wb[32], xw[4];

  // ===== encoder weights/biases -> VGPRs (per wave) =====
  if (li == 0) {
    #pragma unroll
    for (int t = 0; t < 4; ++t)  xw[t] = cvt8(eWih0 + (size_t)wrA * 128 + t * 32 + qo);
    #pragma unroll
    for (int t = 0; t < 16; ++t) wb[t] = cvt8(eWhh0 + (size_t)wrA * 512 + t * 32 + qo);
    #pragma unroll
    for (int r = 0; r < 4; ++r) {
      int wr = r * 512 + rowg * 8 + hf * 4 + q;
      bias[r] = ebi0[wr] + ebh0[wr];
    }
  } else {
    #pragma unroll
    for (int t = 0; t < 16; ++t) wb[t]      = cvt8(eWih1 + (size_t)wrA * 512 + t * 32 + qo);
    #pragma unroll
    for (int t = 0; t < 16; ++t) wb[16 + t] = cvt8(eWhh1 + (size_t)wrA * 512 + t * 32 + qo);
    #pragma unroll
    for (int r = 0; r < 4; ++r) {
      int wr = r * 512 + rowg * 8 + hf * 4 + q;
      bias[r] = ebi1[wr] + ebh1[wr];
    }
  }
  __syncthreads();

  // ================= encoder scan (1 barrier/step) =================
  for (int s = 0; s <= 1024; ++s) {
    const bool L0 = (s < 1024), L1 = (s >= 1);
    const int p = s & 1;
    if (L0) stage_xt(s);
    stage_slot((s + 2) % 3, (s + 1) % 3, true, s >= 1, p);  // h0[s-1], h1[s-2]
    __syncthreads();
    clears(s);

    const u16* hb0 = sH[p][0];
    const u16* hb1 = sH[p][1];
    const bool active = li ? L1 : L0;
    if (active) {
      f32x4 a0 = bias, a1 = {0.f, 0.f, 0.f, 0.f};
      if (li == 0) {
        #pragma unroll
        for (int t = 0; t < 4; ++t) {
          short8 xa = *(const short8*)(sX + m * 136 + t * 32 + qo);
          if (t & 1) a1 = __builtin_amdgcn_mfma_f32_16x16x32_bf16(xw[t], xa, a1, 0, 0, 0);
          else       a0 = __builtin_amdgcn_mfma_f32_16x16x32_bf16(xw[t], xa, a0, 0, 0, 0);
        }
        #pragma unroll
        for (int t = 0; t < 16; ++t) {
          short8 ha = *(const short8*)(hb0 + m * 520 + t * 32 + qo);
          if (t & 1) a1 = __builtin_amdgcn_mfma_f32_16x16x32_bf16(wb[t], ha, a1, 0, 0, 0);
          else       a0 = __builtin_amdgcn_mfma_f32_16x16x32_bf16(wb[t], ha, a0, 0, 0, 0);
        }
        act_store(a0, a1, s % 3);                // h0[s]
      } else {
        #pragma unroll
        for (int t = 0; t < 16; ++t) {
          short8 ha = *(const short8*)(hb0 + m * 520 + t * 32 + qo);
          if (t & 1) a1 = __builtin_amdgcn_mfma_f32_16x16x32_bf16(wb[t], ha, a1, 0, 0, 0);
          else       a0 = __builtin_amdgcn_mfma_f32_16x16x32_bf16(wb[t], ha, a0, 0, 0, 0);
        }
        #pragma unroll
        for (int t = 0; t < 16; ++t) {
          short8 ha = *(const short8*)(hb1 + m * 520 + t * 32 + qo);
          if (t & 1) a1 = __builtin_amdgcn_mfma_f32_16x16x32_bf16(wb[16 + t], ha, a1, 0, 0, 0);
          else       a0 = __builtin_amdgcn_mfma_f32_16x16x32_bf16(wb[16 + t], ha, a0, 0, 0, 0);
        }
        act_store(a0, a1, (s + 2) % 3);          // h1[s-1]
      }
    }
  }

  // ================= latent: z = h1[1023] @ tlW^T + tlb ====================
  u16* sH1z = sH[1][1];                          // free buffer (last step p=0)
  if (tid < 128) {   // h1[1023] in slot 0 (half-major layout)
    const u32* b1 = h1r + ((0 * 4 + col) << 12) + tid;
    u32 v1[32];
    int it = 0; bool ok = false;
    while (!ok && it++ < POLL_CAP) {
      ok = true;
      #pragma unroll
      for (int i = 0; i < 32; ++i) {
        v1[i] = __hip_atomic_load(b1 + i * 128, __ATOMIC_RELAXED, AGENT_SCOPE);
        ok &= (v1[i] != SENT);
      }
    }
    u32* dH1 = (u32*)sH1z;
    #pragma unroll
    for (int i = 0; i < 32; ++i) {
      int g = i * 128 + tid;
      dH1[((g >> 1) & 15) * 260 + (g >> 6) * 4 + ((g >> 5) & 1) * 2 + (g & 1)] = v1[i];
    }
  }
  __syncthreads();
  if (tid < 16) {
    int b = tid;
    float acc = tlb[rowg];
    for (int kk = 0; kk < 512; kk += 8) {
      short8 hv = *(const short8*)(sH1z + b * 520 + kk);
      #pragma unroll
      for (int j = 0; j < 8; ++j) acc += bf2f((u16)hv[j]) * tlW[rowg * 512 + kk + j];
    }
    int gb = col * 16 + b;
    __hip_atomic_store((u32*)zbuf + gb * 64 + rowg, __float_as_uint(acc),
                       __ATOMIC_RELAXED, AGENT_SCOPE);
    out[8388608 + gb * 64 + rowg] = acc;
  }
  gbar(256);        // z visible everywhere; all WGs done with encoder rings

  // ---- reset rings for decoder: all q SENT (own blocks) ----
  if (tid < 64) {
    #pragma unroll
    for (int qq = 0; qq < 3; ++qq) {
      __hip_atomic_store(h0r + ((qq * 4 + col) << 12) + (rowg << 6) + tid,
                         SENT, __ATOMIC_RELAXED, AGENT_SCOPE);
      __hip_atomic_store(h1r + ((qq * 4 + col) << 12) + (rowg << 6) + tid,
                         SENT, __ATOMIC_RELAXED, AGENT_SCOPE);
    }
  }
  wait_vm0();       // clears committed before init_h data stores below

  // ================= decoder weights -> VGPRs ==============================
  short8 rcw[16];
  float opbA = 0.f, opbB = 0.f;
  if (li == 0) {
    #pragma unroll
    for (int t = 0; t < 16; ++t) wb[t] = cvt8(dWhh0 + (size_t)wrA * 512 + t * 32 + qo);
    #pragma unroll
    for (int r = 0; r < 4; ++r) {
      int wr = r * 512 + rowg * 8 + hf * 4 + q;
      bias[r] = dbi0[wr] + dbh0[wr];
    }
    if (hf == 1) {   // wave1 carries recon: A rows 0,1 = opW rows rowg*2+{0,1}
      const short8 z8 = {0, 0, 0, 0, 0, 0, 0, 0};
      #pragma unroll
      for (int t = 0; t < 16; ++t)
        rcw[t] = (m < 2) ? cvt8(opW + (size_t)(rowg * 2 + m) * 512 + t * 32 + qo) : z8;
      opbA = opb[rowg * 2]; opbB = opb[rowg * 2 + 1];
    }
  } else {
    #pragma unroll
    for (int t = 0; t < 16; ++t) wb[t]      = cvt8(dWih1 + (size_t)wrA * 512 + t * 32 + qo);
    #pragma unroll
    for (int t = 0; t < 16; ++t) wb[16 + t] = cvt8(dWhh1 + (size_t)wrA * 512 + t * 32 + qo);
    #pragma unroll
    for (int r = 0; r < 4; ++r) {
      int wr = r * 512 + rowg * 8 + hf * 4 + q;
      bias[r] = dbi1[wr] + dbh1[wr];
    }
  }
  cst = 0.f;

  // ---- init_h = tanh(z @ lhW^T + lhb), torch flat view (L,B,H):
  // init_h[l][bb][h] = M[l*32 + bb/2][(bb&1)*512 + h]; store as h[-1] into q2
  // (half-major offset: (u>>2)*32 + bl*2 + ((u>>1)&1)).
  {
    int ri = tid >> 4, kk = (tid & 15) * 4;
    int zr = ((ri >> 3) << 5) + 8 * col + (ri & 7);
    #pragma unroll
    for (int j = 0; j < 4; ++j)
      sZ[ri * 64 + kk + j] = __uint_as_float(
          __hip_atomic_load((u32*)zbuf + zr * 64 + kk + j, __ATOMIC_RELAXED, AGENT_SCOPE));
  }
  __syncthreads();
  {
    int lli = tid >> 7, hh = (tid >> 4) & 7, qb = (tid >> 3) & 1, u = tid & 7;
    int cc = qb * 512 + rowg * 8 + u;
    int bl = 2 * hh + qb;
    float acc2 = lhb[cc];
    const float* lw = lhW + (size_t)cc * 64;
    #pragma unroll 8
    for (int k = 0; k < 64; ++k) acc2 += sZ[(lli * 8 + hh) * 64 + k] * lw[k];
    u16 hbv = f2bf(tanha(acc2));
    u32 other = __shfl_xor((u32)hbv, 1);
    if (!(u & 1)) {
      u32 v = (u32)hbv | (other << 16);
      u32* ring = lli ? h1r : h0r;
      __hip_atomic_store(ring + ((2 * 4 + col) << 12) + (rowg << 6)
                             + (u >> 2) * 32 + bl * 2 + ((u >> 1) & 1),
                         v, __ATOMIC_RELAXED, AGENT_SCOPE);
    }
  }
  gbar(512);        // ring resets + init data globally visible

  // ================= decoder scan + fused MFMA recon =======================
  for (int s = 0; s <= 1025; ++s) {
    const bool L0 = (s < 1024), L1 = (s >= 1 && s <= 1024), RC = (s >= 2);
    const int p = s & 1;
    stage_slot((s + 2) % 3, (s + 1) % 3, s <= 1024, s >= 1, p);
    __syncthreads();
    clears(s);

    const u16* hb0 = sH[p][0];
    const u16* hb1 = sH[p][1];
    if (li == 0) {
      if (L0) {
        f32x4 a0 = bias, a1 = {0.f, 0.f, 0.f, 0.f};
        #pragma unroll
        for (int t = 0; t < 16; ++t) {
          short8 ha = *(const short8*)(hb0 + m * 520 + t * 32 + qo);
          if (t & 1) a1 = __builtin_amdgcn_mfma_f32_16x16x32_bf16(wb[t], ha, a1, 0, 0, 0);
          else       a0 = __builtin_amdgcn_mfma_f32_16x16x32_bf16(wb[t], ha, a0, 0, 0, 0);
        }
        act_store(a0, a1, s % 3);                // h0[s]
      }
      if (hf == 1 && RC) {   // recon[t=s-2] on wave1, off the h-chain
        f32x4 r0 = {0.f, 0.f, 0.f, 0.f}, r1 = {0.f, 0.f, 0.f, 0.f};
        #pragma unroll
        for (int t = 0; t < 16; ++t) {
          short8 ha = *(const short8*)(hb1 + m * 520 + t * 32 + qo);
          if (t & 1) r1 = __builtin_amdgcn_mfma_f32_16x16x32_bf16(rcw[t], ha, r1, 0, 0, 0);
          else       r0 = __builtin_amdgcn_mfma_f32_16x16x32_bf16(rcw[t], ha, r0, 0, 0, 0);
        }
        if (q == 0) {        // C rows 0,1 = d outputs; col m = batch
          size_t ob = (size_t)(col * 16 + m) * 131072 + (size_t)(s - 2) * 128 + rowg * 2;
          out[ob]     = sigm(r0[0] + r1[0] + opbA);
          out[ob + 1] = sigm(r0[1] + r1[1] + opbB);
        }
      }
    } else {
      if (L1) {
        f32x4 a0 = bias, a1 = {0.f, 0.f, 0.f, 0.f};
        #pragma unroll
        for (int t = 0; t < 16; ++t) {
          short8 ha = *(const short8*)(hb0 + m * 520 + t * 32 + qo);
          if (t & 1) a1 = __builtin_amdgcn_mfma_f32_16x16x32_bf16(wb[t], ha, a1, 0, 0, 0);
          else       a0 = __builtin_amdgcn_mfma_f32_16x16x32_bf16(wb[t], ha, a0, 0, 0, 0);
        }
        #pragma unroll
        for (int t = 0; t < 16; ++t) {
          short8 ha = *(const short8*)(hb1 + m * 520 + t * 32 + qo);
          if (t & 1) a1 = __builtin_amdgcn_mfma_f32_16x16x32_bf16(wb[16 + t], ha, a1, 0, 0, 0);
          else       a0 = __builtin_amdgcn_mfma_f32_16x16x32_bf16(wb[16 + t], ha, a0, 0, 0, 0);
        }
        act_store(a0, a1, (s + 2) % 3);          // h1[s-1]
      }
    }
  }
}

extern "C" void kernel_launch(void* const* d_in, const int* in_sizes, int n_in,
                              void* d_out, int out_size, void* d_ws, size_t ws_size,
                              hipStream_t stream) {
  (void)in_sizes; (void)n_in; (void)out_size; (void)ws_size;
  char* ws = (char*)d_ws;
  // control + zbuf
  (void)hipMemsetAsync(ws, 0, 32768, stream);
  // h0 ring: q0,q1 = SENT (not yet produced), q2 = 0.0 data (h0[-1] = 0)
  (void)hipMemsetAsync(ws + 32768, 0xFF, 131072, stream);
  (void)hipMemsetAsync(ws + 163840, 0x00, 65536, stream);
  // h1 ring: q0,q1 = SENT, q2 = 0.0 data (h1[-1] = 0)
  (void)hipMemsetAsync(ws + 229376, 0xFF, 131072, stream);
  (void)hipMemsetAsync(ws + 360448, 0x00, 65536, stream);
  lstm_ae_kernel<<<dim3(256), dim3(256), 0, stream>>>(
      (const float*)d_in[0],
      (const float*)d_in[1],  (const float*)d_in[2],
      (const float*)d_in[3],  (const float*)d_in[4],
      (const float*)d_in[5],  (const float*)d_in[6],
      (const float*)d_in[7],  (const float*)d_in[8],
      (const float*)d_in[10],
      (const float*)d_in[11], (const float*)d_in[12],
      (const float*)d_in[13], (const float*)d_in[14],
      (const float*)d_in[15], (const float*)d_in[16],
      (const float*)d_in[17], (const float*)d_in[18],
      (const float*)d_in[19], (const float*)d_in[20],
      (const float*)d_in[21], (const float*)d_in[22],
      (float*)d_out, (char*)d_ws);
}

// Round 13
// 5140.284 us; speedup vs baseline: 1.0432x; 1.0432x over previous
//
#include <hip/hip_runtime.h>
#include <cstdint>
#include <cstddef>

typedef unsigned short u16;
typedef unsigned int u32;
typedef __attribute__((ext_vector_type(8))) short short8;
typedef __attribute__((ext_vector_type(4))) float f32x4;

#define AGENT_SCOPE __HIP_MEMORY_SCOPE_AGENT
#define SPIN_CAP 20000000
#define POLL_CAP 200000
#define SENT 0xFFFFFFFFu

__device__ __forceinline__ u16 f2bf(float f) {
  u32 u = __float_as_uint(f);
  return (u16)((u + 0x7FFFu + ((u >> 16) & 1u)) >> 16);
}
__device__ __forceinline__ float bf2f(u16 s) { return __uint_as_float(((u32)s) << 16); }
__device__ __forceinline__ float sigm(float x) { return 1.f / (1.f + __expf(-x)); }
__device__ __forceinline__ float tanha(float x) { return 1.f - 2.f / (__expf(2.f * x) + 1.f); }
__device__ __forceinline__ void wait_vm0() { asm volatile("s_waitcnt vmcnt(0)" ::: "memory"); }
__device__ __forceinline__ u32 um(u32 a, u32 b) { return a > b ? a : b; }

// cache-bypassing agent-visible 16B load (R3/R4-verified semantics)
__device__ __forceinline__ uint4 ldx4(const void* p) {
  uint4 r;
  asm volatile("global_load_dwordx4 %0, %1, off sc0 sc1" : "=v"(r) : "v"(p) : "memory");
  return r;
}

// FINAL KERNEL (R4 structure; best verified 5172-5209us, -18% vs baseline).
// Persistent LSTM autoencoder, barrier-free depth-3 LLC ring exchange with the
// R4 poll de-contention package: (a) dwordx4 fused detect+transfer poll loads,
// (b) sticky per-ring done (h1 has 2-step slack), (c) s_sleep(4) backoff.
//
// SESSION CONCLUSION (R0-R12): step time = agent-scope exchange RTT (~2.5us:
// ~0.7us store->LLC-visibility + ~1us loaded poll + ~0.5us compute) x 2051
// sequential steps. Counters far from HW rooflines (HBM 2.3%, Mfma 6.7%) —
// this is a LATENCY floor, established by exhaustion:
//  - poll traffic: R4 -18% (won); R3 monotone worse with more traffic
//  - detect-then-fetch flags: R2 worse (+2 LLC hops; 1 hop ~= 0.9-1.1us)
//  - VALU/barrier/act structure: R1 neutral, R6 worse, R12 (fixed layout:
//    WRITE 853->591MB, VALU 13.8%) still +4% => act path off critical path
//  - poll cadence pipelining, store gathering: R9 null
//  - XCD-local L2 exchange: R10 NaN (no HIP XCD scope; placement unprovable)
// Weight capacity (Whh bf16 = 2MB/layer >> 160KB LDS) forces hidden-split,
// which forces the per-step all-to-all. The exchange is irreducible here.
__global__ void __launch_bounds__(256, 1)
lstm_ae_kernel(const float* __restrict__ x,
    const float* __restrict__ eWih0, const float* __restrict__ eWhh0,
    const float* __restrict__ ebi0,  const float* __restrict__ ebh0,
    const float* __restrict__ eWih1, const float* __restrict__ eWhh1,
    const float* __restrict__ ebi1,  const float* __restrict__ ebh1,
    const float* __restrict__ dWhh0,
    const float* __restrict__ dbi0,  const float* __restrict__ dbh0,
    const float* __restrict__ dWih1, const float* __restrict__ dWhh1,
    const float* __restrict__ dbi1,  const float* __restrict__ dbh1,
    const float* __restrict__ tlW,   const float* __restrict__ tlb,
    const float* __restrict__ lhW,   const float* __restrict__ lhb,
    const float* __restrict__ opW,   const float* __restrict__ opb,
    float* __restrict__ out, char* __restrict__ wsb)
{
  __shared__ __align__(16) u16 sH0[16 * 520];   // staged h0 bf16, row stride 520
  __shared__ __align__(16) u16 sH1[16 * 520];
  __shared__ __align__(16) u16 sX[16 * 136];
  __shared__ __align__(16) u16 sOPW[2 * 520];
  __shared__ float sP[4 * 256];                  // per-wave MFMA partials [16b][16n]
  __shared__ float sBias[64];                    // [2 layer][32 gate-rows]
  __shared__ float sC[256];                      // [2][16 b][8 u] cell state fp32
  __shared__ float sZ[16 * 64];
  __shared__ float sOPB[4];

  u32* gcnt  = (u32*)wsb;
  float* zbuf= (float*)(wsb + 4096);             // [64][64]
  u32* h0r   = (u32*)(wsb + 32768);              // [3 q][4 col][64 rowg][64 dw]
  u32* h1r   = (u32*)(wsb + 229376);             // same (196608 B each)

  const int tid  = threadIdx.x;
  const int col  = blockIdx.x & 3;
  const int rowg = blockIdx.x >> 2;              // 0..63
  const int wid  = tid >> 6;
  const int lane = tid & 63;
  const int m    = lane & 15;
  const int qo   = (lane >> 4) * 8;

  // ---------- helpers ----------
  // poll+stage one slot's h0 (q0) and optionally h1 (q1) column images into LDS.
  // Vectorized (x4) fused detect+transfer with sticky per-ring done + backoff.
  auto stage_slot = [&](int q0, int q1, bool p0on, bool p1on) {
    const char* base0 = (const char*)(h0r + ((q0 * 4 + col) << 12)) + tid * 16;
    const char* base1 = (const char*)(h1r + ((q1 * 4 + col) << 12)) + tid * 16;
    uint4 v0[4], v1[4];
    bool d0 = !p0on, d1 = !p1on;
    int it = 0;
    for (;;) {
      if (!d0) {
        #pragma unroll
        for (int i = 0; i < 4; ++i) v0[i] = ldx4(base0 + i * 4096);
      }
      if (!d1) {
        #pragma unroll
        for (int i = 0; i < 4; ++i) v1[i] = ldx4(base1 + i * 4096);
      }
      asm volatile("s_waitcnt vmcnt(0)" ::: "memory");
      __builtin_amdgcn_sched_barrier(0);
      if (!d0) {
        u32 mx = 0;
        #pragma unroll
        for (int i = 0; i < 4; ++i)
          mx = um(mx, um(um(v0[i].x, v0[i].y), um(v0[i].z, v0[i].w)));
        d0 = (mx != SENT);
      }
      if (!d1) {
        u32 mx = 0;
        #pragma unroll
        for (int i = 0; i < 4; ++i)
          mx = um(mx, um(um(v1[i].x, v1[i].y), um(v1[i].z, v1[i].w)));
        d1 = (mx != SENT);
      }
      if ((d0 && d1) || ++it >= POLL_CAP) break;
      __builtin_amdgcn_s_sleep(4);
    }
    // LDS scatter: dword g = i*1024 + tid*4 + j  ->  b=(tid&15), rg=i*16+(tid>>4)
    u32* dH0 = (u32*)sH0; u32* dH1 = (u32*)sH1;
    const int db = (tid & 15) * 260 + (tid >> 4) * 4;
    if (p0on) {
      #pragma unroll
      for (int i = 0; i < 4; ++i) *(uint4*)(dH0 + db + i * 64) = v0[i];
    }
    if (p1on) {
      #pragma unroll
      for (int i = 0; i < 4; ++i) *(uint4*)(dH1 + db + i * 64) = v1[i];
    }
  };

  // SENT-clear own blocks of the buffers reused at slot s+1 (issued during compute;
  // drained by act's wait_vm0, i.e. before this slot's data stores land)
  auto clears = [&](int s) {
    if (tid < 64) {
      int cq0 = (s + 1) % 3, cq1 = s % 3;
      __hip_atomic_store(h0r + ((cq0 * 4 + col) << 12) + (rowg << 6) + tid,
                         SENT, __ATOMIC_RELAXED, AGENT_SCOPE);
      __hip_atomic_store(h1r + ((cq1 * 4 + col) << 12) + (rowg << 6) + tid,
                         SENT, __ATOMIC_RELAXED, AGENT_SCOPE);
    }
  };

  auto stage_xt = [&](int s) {
    int b = tid >> 4, seg = tid & 15;
    const float* p = x + (size_t)(col * 16 + b) * 131072 + (size_t)s * 128 + seg * 8;
    float4 f0 = *(const float4*)p, f1 = *(const float4*)(p + 4);
    uint4 v;
    v.x = (u32)f2bf(f0.x) | ((u32)f2bf(f0.y) << 16);
    v.y = (u32)f2bf(f0.z) | ((u32)f2bf(f0.w) << 16);
    v.z = (u32)f2bf(f1.x) | ((u32)f2bf(f1.y) << 16);
    v.w = (u32)f2bf(f1.z) | ((u32)f2bf(f1.w) << 16);
    *(uint4*)(sX + b * 136 + seg * 8) = v;
  };

  // B-fragment loader: weight row, bf16-converted, k window kofs+qo..+8
  auto ldw = [&](const float* W, int ld, int row, int kofs) -> short8 {
    const float* p = W + (size_t)row * ld + kofs + qo;
    float4 f0 = *(const float4*)p, f1 = *(const float4*)(p + 4);
    short8 r;
    r[0] = (short)f2bf(f0.x); r[1] = (short)f2bf(f0.y);
    r[2] = (short)f2bf(f0.z); r[3] = (short)f2bf(f0.w);
    r[4] = (short)f2bf(f1.x); r[5] = (short)f2bf(f1.y);
    r[6] = (short)f2bf(f1.z); r[7] = (short)f2bf(f1.w);
    return r;
  };

  // gates (R2-verified mapping): L0 slots 0,1; L1 slots 2,3.
  auto act_store = [&](bool L0a, bool L1a, int q0, int q1) {
    int li = tid >> 7, b = (tid >> 3) & 15, u = tid & 7;
    bool actv = li ? L1a : L0a;
    float hv = 0.f;
    if (actv) {
      float gi = sP[(li*2)*256   + b*16 + u]     + sBias[li*32 + u];
      float gf = sP[(li*2)*256   + b*16 + 8 + u] + sBias[li*32 + 8 + u];
      float gg = sP[(li*2+1)*256 + b*16 + u]     + sBias[li*32 + 16 + u];
      float go = sP[(li*2+1)*256 + b*16 + 8 + u] + sBias[li*32 + 24 + u];
      float c = sC[(li*16 + b)*8 + u];
      c = sigm(gf)*c + sigm(gi)*tanha(gg);
      sC[(li*16 + b)*8 + u] = c;
      hv = sigm(go)*tanha(c);
    }
    u16 hb = f2bf(hv);
    u32 other = __shfl_xor((u32)hb, 1);
    if (actv && !(u & 1)) {
      u32 v = (u32)hb | (other << 16);
      u32* ring = li ? h1r : h0r;
      int q = li ? q1 : q0;
      __hip_atomic_store(ring + ((q * 4 + col) << 12) + (rowg << 6) + b * 4 + (u >> 1),
                         v, __ATOMIC_RELAXED, AGENT_SCOPE);
    }
  };

  auto gbar = [&](u32 target) {
    __syncthreads();
    if (tid == 0) {
      __hip_atomic_fetch_add(gcnt, 1u, __ATOMIC_RELEASE, AGENT_SCOPE);
      int it = 0;
      while (__hip_atomic_load(gcnt, __ATOMIC_RELAXED, AGENT_SCOPE) < target && ++it < SPIN_CAP) {}
      (void)__hip_atomic_load(gcnt, __ATOMIC_ACQUIRE, AGENT_SCOPE);
    }
    __syncthreads();
  };

  // lane's weight row: n = (wid&1)*16 + m; gate = n>>3, unit = n&7
  const int nl = (wid & 1) * 16 + m;
  const int gw = ((nl >> 3) << 9) + rowg * 8 + (nl & 7);

  short8 wb[32];

  // ================= encoder weights -> VGPRs =================
  if (wid < 2) {
    #pragma unroll
    for (int t = 0; t < 4; ++t)  wb[t]      = ldw(eWih0, 128, gw, t * 32);
    #pragma unroll
    for (int t = 0; t < 16; ++t) wb[4 + t]  = ldw(eWhh0, 512, gw, t * 32);
  } else {
    #pragma unroll
    for (int t = 0; t < 16; ++t) wb[t]      = ldw(eWih1, 512, gw, t * 32);
    #pragma unroll
    for (int t = 0; t < 16; ++t) wb[16 + t] = ldw(eWhh1, 512, gw, t * 32);
  }
  if (tid < 64) {
    int li = tid >> 5, n = tid & 31;
    int g = ((n >> 3) << 9) + rowg * 8 + (n & 7);
    sBias[li * 32 + n] = li ? (ebi1[g] + ebh1[g]) : (ebi0[g] + ebh0[g]);
  }
  sC[tid] = 0.f;
  __syncthreads();

  // ================= encoder scan (lag-1 pipelined, barrier-free) =====
  for (int s = 0; s <= 1024; ++s) {
    const bool L0 = (s < 1024), L1 = (s >= 1);
    if (L0) stage_xt(s);
    stage_slot((s + 2) % 3, (s + 1) % 3, true, s >= 1);   // h0[s-1], h1[s-2]
    __syncthreads();
    clears(s);

    f32x4 acc = {0.f, 0.f, 0.f, 0.f};
    if (wid < 2) {
      if (L0) {
        #pragma unroll
        for (int t = 0; t < 4; ++t) {
          short8 a = *(const short8*)(sX + m * 136 + t * 32 + qo);
          acc = __builtin_amdgcn_mfma_f32_16x16x32_bf16(a, wb[t], acc, 0, 0, 0);
        }
        #pragma unroll
        for (int t = 0; t < 16; ++t) {
          short8 a = *(const short8*)(sH0 + m * 520 + t * 32 + qo);
          acc = __builtin_amdgcn_mfma_f32_16x16x32_bf16(a, wb[4 + t], acc, 0, 0, 0);
        }
      }
    } else {
      if (L1) {
        #pragma unroll
        for (int t = 0; t < 16; ++t) {
          short8 a = *(const short8*)(sH0 + m * 520 + t * 32 + qo);
          acc = __builtin_amdgcn_mfma_f32_16x16x32_bf16(a, wb[t], acc, 0, 0, 0);
        }
        #pragma unroll
        for (int t = 0; t < 16; ++t) {
          short8 a = *(const short8*)(sH1 + m * 520 + t * 32 + qo);
          acc = __builtin_amdgcn_mfma_f32_16x16x32_bf16(a, wb[16 + t], acc, 0, 0, 0);
        }
      }
    }
    {
      bool wact = (wid < 2) ? L0 : L1;
      if (wact) {
        int mb = (lane >> 4) * 4;
        #pragma unroll
        for (int r = 0; r < 4; ++r) sP[wid * 256 + (mb + r) * 16 + m] = acc[r];
      }
    }
    __syncthreads();                       // sP visible
    {
      // drain clears before data stores (act_store stores ring data)
      wait_vm0();
    }
    act_store(L0, L1, s % 3, (s + 2) % 3); // h0[s] -> q s%3, h1[s-1] -> q (s-1)%3
  }

  // ================= latent: z = h1[1023] @ tlW^T + tlb ====================
  {  // h1[1023] is in h1 ring q0 (stored at slot 1024)
    const u32* b1 = h1r + ((0 * 4 + col) << 12) + tid;
    u32 v1[16];
    int it = 0; bool ok = false;
    while (!ok && it++ < POLL_CAP) {
      ok = true;
      #pragma unroll
      for (int i = 0; i < 16; ++i) {
        v1[i] = __hip_atomic_load(b1 + i * 256, __ATOMIC_RELAXED, AGENT_SCOPE);
        ok &= (v1[i] != SENT);
      }
    }
    u32* dH1 = (u32*)sH1;
    #pragma unroll
    for (int i = 0; i < 16; ++i) {
      int g = i * 256 + tid;
      dH1[((g >> 2) & 15) * 260 + (g >> 6) * 4 + (g & 3)] = v1[i];
    }
  }
  __syncthreads();
  if (tid < 16) {
    int b = tid;
    float acc = tlb[rowg];
    for (int kk = 0; kk < 512; kk += 8) {
      short8 hv = *(const short8*)(sH1 + b * 520 + kk);
      #pragma unroll
      for (int j = 0; j < 8; ++j) acc += bf2f((u16)hv[j]) * tlW[rowg * 512 + kk + j];
    }
    int gb = col * 16 + b;
    __hip_atomic_store((u32*)zbuf + gb * 64 + rowg, __float_as_uint(acc),
                       __ATOMIC_RELAXED, AGENT_SCOPE);
    out[8388608 + gb * 64 + rowg] = acc;
  }
  gbar(256);        // z visible everywhere; all WGs done with encoder rings

  // ---- reset rings for decoder: all q SENT (own blocks) ----
  if (tid < 64) {
    #pragma unroll
    for (int q = 0; q < 3; ++q) {
      __hip_atomic_store(h0r + ((q * 4 + col) << 12) + (rowg << 6) + tid,
                         SENT, __ATOMIC_RELAXED, AGENT_SCOPE);
      __hip_atomic_store(h1r + ((q * 4 + col) << 12) + (rowg << 6) + tid,
                         SENT, __ATOMIC_RELAXED, AGENT_SCOPE);
    }
  }
  wait_vm0();       // clears committed before init_h data stores below

  // ================= decoder weights -> VGPRs ==============================
  if (wid < 2) {
    #pragma unroll
    for (int t = 0; t < 16; ++t) wb[t] = ldw(dWhh0, 512, gw, t * 32);
  } else {
    #pragma unroll
    for (int t = 0; t < 16; ++t) wb[t]      = ldw(dWih1, 512, gw, t * 32);
    #pragma unroll
    for (int t = 0; t < 16; ++t) wb[16 + t] = ldw(dWhh1, 512, gw, t * 32);
  }
  if (tid < 64) {
    int li = tid >> 5, n = tid & 31;
    int g = ((n >> 3) << 9) + rowg * 8 + (n & 7);
    sBias[li * 32 + n] = li ? (dbi1[g] + dbh1[g]) : (dbi0[g] + dbh0[g]);
  }
  for (int i = tid; i < 2 * 64; i += 256) {      // opW rows rowg*2, rowg*2+1
    int dd = i >> 6, k = (i & 63) * 8;
    const float* p = opW + (size_t)(rowg * 2 + dd) * 512 + k;
    float4 f0 = *(const float4*)p, f1 = *(const float4*)(p + 4);
    uint4 v;
    v.x = (u32)f2bf(f0.x) | ((u32)f2bf(f0.y) << 16);
    v.y = (u32)f2bf(f0.z) | ((u32)f2bf(f0.w) << 16);
    v.z = (u32)f2bf(f1.x) | ((u32)f2bf(f1.y) << 16);
    v.w = (u32)f2bf(f1.z) | ((u32)f2bf(f1.w) << 16);
    *(uint4*)(sOPW + dd * 520 + k) = v;
  }
  if (tid < 2) sOPB[tid] = opb[rowg * 2 + tid];
  sC[tid] = 0.f;

  // ---- init_h = tanh(z @ lhW^T + lhb), torch flat view (L,B,H):
  // init_h[l][bb][h] = M[l*32 + bb/2][(bb&1)*512 + h]; store as h[-1] into q2.
  {
    int ri = tid >> 4, kk = (tid & 15) * 4;
    int zr = ((ri >> 3) << 5) + 8 * col + (ri & 7);
    #pragma unroll
    for (int j = 0; j < 4; ++j)
      sZ[ri * 64 + kk + j] = __uint_as_float(
          __hip_atomic_load((u32*)zbuf + zr * 64 + kk + j, __ATOMIC_RELAXED, AGENT_SCOPE));
  }
  __syncthreads();
  {
    int li = tid >> 7, hh = (tid >> 4) & 7, qb = (tid >> 3) & 1, u = tid & 7;
    int cc = qb * 512 + rowg * 8 + u;
    int bl = 2 * hh + qb;
    float acc2 = lhb[cc];
    const float* lw = lhW + (size_t)cc * 64;
    #pragma unroll 8
    for (int k = 0; k < 64; ++k) acc2 += sZ[(li * 8 + hh) * 64 + k] * lw[k];
    u16 hb = f2bf(tanha(acc2));
    u32 other = __shfl_xor((u32)hb, 1);
    if (!(u & 1)) {
      u32 v = (u32)hb | (other << 16);
      u32* ring = li ? h1r : h0r;
      __hip_atomic_store(ring + ((2 * 4 + col) << 12) + (rowg << 6) + bl * 4 + (u >> 1),
                         v, __ATOMIC_RELAXED, AGENT_SCOPE);
    }
  }
  gbar(512);        // ring resets globally visible before any decoder poll

  // ================= decoder scan + fused recon ============================
  for (int s = 0; s <= 1025; ++s) {
    const bool L0 = (s < 1024), L1 = (s >= 1 && s <= 1024), RC = (s >= 2);
    stage_slot((s + 2) % 3, (s + 1) % 3, s <= 1024, s >= 1);
    __syncthreads();
    clears(s);

    f32x4 acc = {0.f, 0.f, 0.f, 0.f};
    if (wid < 2) {
      if (L0) {
        #pragma unroll
        for (int t = 0; t < 16; ++t) {
          short8 a = *(const short8*)(sH0 + m * 520 + t * 32 + qo);
          acc = __builtin_amdgcn_mfma_f32_16x16x32_bf16(a, wb[t], acc, 0, 0, 0);
        }
      }
    } else {
      if (L1) {
        #pragma unroll
        for (int t = 0; t < 16; ++t) {
          short8 a = *(const short8*)(sH0 + m * 520 + t * 32 + qo);
          acc = __builtin_amdgcn_mfma_f32_16x16x32_bf16(a, wb[t], acc, 0, 0, 0);
        }
        #pragma unroll
        for (int t = 0; t < 16; ++t) {
          short8 a = *(const short8*)(sH1 + m * 520 + t * 32 + qo);
          acc = __builtin_amdgcn_mfma_f32_16x16x32_bf16(a, wb[16 + t], acc, 0, 0, 0);
        }
      }
    }
    {
      bool wact = (wid < 2) ? L0 : L1;
      if (wact) {
        int mb = (lane >> 4) * 4;
        #pragma unroll
        for (int r = 0; r < 4; ++r) sP[wid * 256 + (mb + r) * 16 + m] = acc[r];
      }
    }
    __syncthreads();
    wait_vm0();                            // drains clears before data stores
    act_store(L0, L1, s % 3, (s + 2) % 3);

    if (RC) {   // recon[t=s-2] = sigmoid(h1dec[s-2] @ opW^T + opb), d = rowg*2+{0,1}
      __syncthreads();
      int b = tid >> 4, dd = (tid >> 3) & 1, pt = tid & 7;
      float acc2 = 0.f;
      int k0 = pt * 64;
      for (int kk = 0; kk < 64; kk += 8) {
        short8 hv = *(const short8*)(sH1 + b * 520 + k0 + kk);
        short8 wv = *(const short8*)(sOPW + dd * 520 + k0 + kk);
        #pragma unroll
        for (int j = 0; j < 8; ++j) acc2 += bf2f((u16)hv[j]) * bf2f((u16)wv[j]);
      }
      sP[tid] = acc2;
      __syncthreads();
      if (tid < 32) {
        int b2 = tid >> 1, d2 = tid & 1;
        float sum = sOPB[d2];
        #pragma unroll
        for (int j = 0; j < 8; ++j) sum += sP[b2 * 16 + d2 * 8 + j];
        out[(size_t)(col * 16 + b2) * 131072 + (size_t)(s - 2) * 128 + rowg * 2 + d2]
            = sigm(sum);
      }
    }
  }
}

extern "C" void kernel_launch(void* const* d_in, const int* in_sizes, int n_in,
                              void* d_out, int out_size, void* d_ws, size_t ws_size,
                              hipStream_t stream) {
  (void)in_sizes; (void)n_in; (void)out_size; (void)ws_size;
  char* ws = (char*)d_ws;
  // control + zbuf
  (void)hipMemsetAsync(ws, 0, 32768, stream);
  // h0 ring: q0,q1 = SENT (not yet produced), q2 = 0.0 data (h0[-1] = 0)
  (void)hipMemsetAsync(ws + 32768, 0xFF, 131072, stream);
  (void)hipMemsetAsync(ws + 163840, 0x00, 65536, stream);
  // h1 ring: q0,q1 = SENT, q2 = 0.0 data (h1[-1] = 0)
  (void)hipMemsetAsync(ws + 229376, 0xFF, 131072, stream);
  (void)hipMemsetAsync(ws + 360448, 0x00, 65536, stream);
  lstm_ae_kernel<<<dim3(256), dim3(256), 0, stream>>>(
      (const float*)d_in[0],
      (const float*)d_in[1],  (const float*)d_in[2],
      (const float*)d_in[3],  (const float*)d_in[4],
      (const float*)d_in[5],  (const float*)d_in[6],
      (const float*)d_in[7],  (const float*)d_in[8],
      (const float*)d_in[10],
      (const float*)d_in[11], (const float*)d_in[12],
      (const float*)d_in[13], (const float*)d_in[14],
      (const float*)d_in[15], (const float*)d_in[16],
      (const float*)d_in[17], (const float*)d_in[18],
      (const float*)d_in[19], (const float*)d_in[20],
      (const float*)d_in[21], (const float*)d_in[22],
      (float*)d_out, (char*)d_ws);
}